// Round 1
// baseline (474.080 us; speedup 1.0000x reference)
//
#include <hip/hip_runtime.h>

// SwinAttention1D fused: B=8, C=256, N=16384, W=16, H=4, hd=64.
// One block = 2 consecutive windows (32 consecutive tokens n). bf16 MFMA for
// qkv/attn/out-proj, fp32 softmax/LN. Weights pre-converted to bf16 in d_ws.

#define C_DIM 256
#define NSEQ  16384

typedef __attribute__((ext_vector_type(8))) short bf16x8;
typedef __attribute__((ext_vector_type(4))) float f32x4;

__device__ __forceinline__ unsigned short f2bf(float f) {
    unsigned int u = __builtin_bit_cast(unsigned int, f);
    u += 0x7FFFu + ((u >> 16) & 1u);   // RNE
    return (unsigned short)(u >> 16);
}
__device__ __forceinline__ float bf2f(unsigned short h) {
    unsigned int u = ((unsigned int)h) << 16;
    return __builtin_bit_cast(float, u);
}

__global__ void prep_weights(const float* __restrict__ wq_f, const float* __restrict__ wo_f,
                             unsigned short* __restrict__ wq, unsigned short* __restrict__ wo) {
    int i = blockIdx.x * 256 + threadIdx.x;
    if (i < 768 * 256) wq[i] = f2bf(wq_f[i]);
    if (i < 256 * 256) wo[i] = f2bf(wo_f[i]);
}

__global__ __launch_bounds__(256, 2) void swin_fused(
    const float* __restrict__ x,
    const unsigned short* __restrict__ wq,   // bf16 [768][256]
    const unsigned short* __restrict__ wo,   // bf16 [256][256]
    const float* __restrict__ bq,
    const float* __restrict__ bo,
    const float* __restrict__ lng,
    const float* __restrict__ lnb,
    float* __restrict__ out)
{
    // token-major x tile (rows 16B-aligned: 264*2 = 528 = 16*33)
    __shared__ __align__(16) unsigned short lds_x[32][264];
    // cols 0-255: q (later overwritten by attn), 256-511: k. stride 520*2=1040=16*65
    __shared__ __align__(16) unsigned short lds_qk[32][520];
    // v transposed: [channel 0..255][token 0..31], stride 40*2=80=16*5
    __shared__ __align__(16) unsigned short lds_vt[256][40];
    // probs staging, one slot per (wave, iter); stride 24*2=48=16*3
    __shared__ __align__(16) unsigned short lds_p[8][16][24];
    __shared__ float lds_mean[32];
    __shared__ float lds_rstd[32];

    const int tid  = threadIdx.x;
    const int wv   = tid >> 6;
    const int lane = tid & 63;
    const int l15  = lane & 15;
    const int quad = lane >> 4;

    const int w0    = blockIdx.x * 2;          // first window of this block
    const int batch = w0 >> 10;                // 1024 windows per batch image
    const int nbase = (w0 & 1023) << 4;        // starting n; 32 consecutive tokens
    const long xbase = (long)batch * ((long)C_DIM * NSEQ) + nbase;

    // ---------- Phase 1: load x tile (32 tokens x 256 ch), convert bf16 ----------
    {
        const int t  = tid & 31;               // token (consecutive n -> coalesced)
        const int c0 = tid >> 5;               // 0..7
        #pragma unroll 4
        for (int it = 0; it < 32; ++it) {
            int c = (it << 3) + c0;
            lds_x[t][c] = f2bf(x[xbase + (long)c * NSEQ + t]);
        }
    }
    __syncthreads();

    // ---------- Phase 2: QKV = x @ Wqkv^T + b ----------
    // tiles: 2 M-tiles x 48 N-tiles; wave wv does nt = 4i+wv, reuses B-frags across mt.
    for (int i = 0; i < 12; ++i) {
        const int nt = (i << 2) + wv;          // 0..47
        const int d  = nt * 16 + l15;          // output channel 0..767
        const unsigned short* wrow = wq + d * 256 + quad * 8;
        bf16x8 bfr[8];
        #pragma unroll
        for (int k = 0; k < 8; ++k)
            bfr[k] = *reinterpret_cast<const bf16x8*>(wrow + k * 32);
        const float bias = bq[d];
        #pragma unroll
        for (int mt = 0; mt < 2; ++mt) {
            f32x4 acc = {bias, bias, bias, bias};
            #pragma unroll
            for (int k = 0; k < 8; ++k) {
                bf16x8 a = *reinterpret_cast<const bf16x8*>(&lds_x[mt * 16 + l15][k * 32 + quad * 8]);
                acc = __builtin_amdgcn_mfma_f32_16x16x32_bf16(a, bfr[k], acc, 0, 0, 0);
            }
            #pragma unroll
            for (int r = 0; r < 4; ++r) {
                const int row = mt * 16 + quad * 4 + r;        // token in block
                const unsigned short hv = f2bf(acc[r]);
                if (d < 512) lds_qk[row][d]       = hv;        // q | k
                else         lds_vt[d - 512][row] = hv;        // v transposed
            }
        }
    }
    __syncthreads();

    // ---------- Phase 3: windowed attention, 2 (window g, head h) pairs per wave ----------
    for (int it = 0; it < 2; ++it) {
        const int p = wv * 2 + it;
        const int g = p >> 2;                  // window in block (0/1)
        const int h = p & 3;                   // head
        // scores = q @ k^T  (K=64 -> 2 MFMA steps); B-frag of k^T == A-frag of k
        f32x4 sc = {0.f, 0.f, 0.f, 0.f};
        #pragma unroll
        for (int kk = 0; kk < 2; ++kk) {
            bf16x8 aq = *reinterpret_cast<const bf16x8*>(&lds_qk[g*16 + l15][h*64 + kk*32 + quad*8]);
            bf16x8 bk = *reinterpret_cast<const bf16x8*>(&lds_qk[g*16 + l15][256 + h*64 + kk*32 + quad*8]);
            sc = __builtin_amdgcn_mfma_f32_16x16x32_bf16(aq, bk, sc, 0, 0, 0);
        }
        // softmax over k (cols = 16 lanes of this quad), rows = quad*4+r
        const int slot = wv * 2 + it;
        #pragma unroll
        for (int r = 0; r < 4; ++r) {
            float s = sc[r] * 0.125f;          // 1/sqrt(hd)
            float m = s;
            #pragma unroll
            for (int msk = 1; msk <= 8; msk <<= 1) m = fmaxf(m, __shfl_xor(m, msk, 16));
            float e = __expf(s - m);
            float su = e;
            #pragma unroll
            for (int msk = 1; msk <= 8; msk <<= 1) su += __shfl_xor(su, msk, 16);
            lds_p[slot][quad * 4 + r][l15] = f2bf(e / su);   // C-layout -> (q,k) matrix
        }
        __syncthreads();
        // attn = P @ v : K=16 padded to 32 (quads 2,3 zeroed on BOTH operands)
        #pragma unroll
        for (int dt = 0; dt < 4; ++dt) {
            bf16x8 ap = {0,0,0,0,0,0,0,0};
            bf16x8 bv = {0,0,0,0,0,0,0,0};
            if (quad < 2) {
                ap = *reinterpret_cast<const bf16x8*>(&lds_p[slot][l15][quad * 8]);
                bv = *reinterpret_cast<const bf16x8*>(&lds_vt[h*64 + dt*16 + l15][g*16 + quad*8]);
            }
            f32x4 acc = {0.f, 0.f, 0.f, 0.f};
            acc = __builtin_amdgcn_mfma_f32_16x16x32_bf16(ap, bv, acc, 0, 0, 0);
            #pragma unroll
            for (int r = 0; r < 4; ++r)   // overlay attn onto q region (disjoint from remaining q reads)
                lds_qk[g*16 + quad*4 + r][h*64 + dt*16 + l15] = f2bf(acc[r]);
        }
    }
    __syncthreads();

    // ---------- Phase 4: out = attn @ Wo^T + b_o; y = out + x  (y bf16, overlaid on lds_vt) ----------
    unsigned short* ldy = &lds_vt[0][0];       // 32*264 = 8448 shorts <= 10240
    for (int i = 0; i < 4; ++i) {
        const int nt = (i << 2) + wv;          // 0..15
        const int d  = nt * 16 + l15;          // 0..255
        const unsigned short* wrow = wo + d * 256 + quad * 8;
        bf16x8 bfr[8];
        #pragma unroll
        for (int k = 0; k < 8; ++k)
            bfr[k] = *reinterpret_cast<const bf16x8*>(wrow + k * 32);
        const float bias = bo[d];
        #pragma unroll
        for (int mt = 0; mt < 2; ++mt) {
            f32x4 acc = {bias, bias, bias, bias};
            #pragma unroll
            for (int k = 0; k < 8; ++k) {
                bf16x8 a = *reinterpret_cast<const bf16x8*>(&lds_qk[mt*16 + l15][k*32 + quad*8]);
                acc = __builtin_amdgcn_mfma_f32_16x16x32_bf16(a, bfr[k], acc, 0, 0, 0);
            }
            #pragma unroll
            for (int r = 0; r < 4; ++r) {
                const int row = mt * 16 + quad * 4 + r;
                const float yv = acc[r] + bf2f(lds_x[row][d]);   // residual
                ldy[row * 264 + d] = f2bf(yv);
            }
        }
    }
    __syncthreads();

    // ---------- Phase 5a: LN stats (8 threads per token row) ----------
    {
        const int row = tid >> 3, part = tid & 7;
        float s = 0.f, sq = 0.f;
        #pragma unroll 8
        for (int ii = 0; ii < 32; ++ii) {
            float v = bf2f(ldy[row * 264 + part * 32 + ii]);
            s += v; sq += v * v;
        }
        #pragma unroll
        for (int msk = 1; msk <= 4; msk <<= 1) {
            s  += __shfl_xor(s,  msk, 8);
            sq += __shfl_xor(sq, msk, 8);
        }
        if (part == 0) {
            float mean = s * (1.0f / 256.0f);
            float var  = sq * (1.0f / 256.0f) - mean * mean;
            lds_mean[row] = mean;
            lds_rstd[row] = rsqrtf(var + 1e-5f);
        }
    }
    __syncthreads();

    // ---------- Phase 5b: normalize + transposed coalesced store ----------
    {
        const int t  = tid & 31;
        const int cb = (tid >> 5) * 32;
        const float mean = lds_mean[t];
        const float rstd = lds_rstd[t];
        #pragma unroll 4
        for (int ii = 0; ii < 32; ++ii) {
            int c = cb + ii;
            float v = (bf2f(ldy[t * 264 + c]) - mean) * rstd * lng[c] + lnb[c];
            out[xbase + (long)c * NSEQ + t] = v;
        }
    }
}

extern "C" void kernel_launch(void* const* d_in, const int* in_sizes, int n_in,
                              void* d_out, int out_size, void* d_ws, size_t ws_size,
                              hipStream_t stream) {
    const float* x   = (const float*)d_in[0];
    const float* ipw = (const float*)d_in[1];   // (768,256)
    const float* ipb = (const float*)d_in[2];   // (768,)
    const float* opw = (const float*)d_in[3];   // (256,256)
    const float* opb = (const float*)d_in[4];   // (256,)
    const float* lng = (const float*)d_in[5];   // (256,)
    const float* lnb = (const float*)d_in[6];   // (256,)
    float* out = (float*)d_out;

    unsigned short* wq = (unsigned short*)d_ws;          // 768*256 bf16
    unsigned short* wo = wq + 768 * 256;                 // 256*256 bf16

    prep_weights<<<768, 256, 0, stream>>>(ipw, opw, wq, wo);
    swin_fused<<<4096, 256, 0, stream>>>(x, wq, wo, ipb, opb, lng, lnb, out);
}

// Round 3
// 436.385 us; speedup vs baseline: 1.0864x; 1.0864x over previous
//
#include <hip/hip_runtime.h>

// SwinAttention1D fused: B=8, C=256, N=16384, W=16, H=4, hd=64.
// One block = 2 windows (32 tokens), 512 threads (8 waves), 2 blocks/CU.

#define C_DIM 256
#define NSEQ  16384

typedef __attribute__((ext_vector_type(8))) short bf16x8;
typedef __attribute__((ext_vector_type(4))) float f32x4;

__device__ __forceinline__ unsigned short f2bf(float f) {
    unsigned int u = __builtin_bit_cast(unsigned int, f);
    u += 0x7FFFu + ((u >> 16) & 1u);   // RNE
    return (unsigned short)(u >> 16);
}
__device__ __forceinline__ float bf2f(unsigned short h) {
    unsigned int u = ((unsigned int)h) << 16;
    return __builtin_bit_cast(float, u);
}
__device__ __forceinline__ unsigned int pack2(float a, float b) {
    return ((unsigned int)f2bf(b) << 16) | (unsigned int)f2bf(a);
}

__global__ void prep_weights(const float* __restrict__ wq_f, const float* __restrict__ wo_f,
                             unsigned short* __restrict__ wq, unsigned short* __restrict__ wo) {
    int i = blockIdx.x * 256 + threadIdx.x;
    if (i < 768 * 256) wq[i] = f2bf(wq_f[i]);
    if (i < 256 * 256) wo[i] = f2bf(wo_f[i]);
}

__global__ __launch_bounds__(512, 4) void swin_fused(
    const float* __restrict__ x,
    const unsigned short* __restrict__ wq,   // bf16 [768][256]
    const unsigned short* __restrict__ wo,   // bf16 [256][256]
    const float* __restrict__ bq,
    const float* __restrict__ bo,
    const float* __restrict__ lng,
    const float* __restrict__ lnb,
    float* __restrict__ out)
{
    // token-major x tile, rows 16B-aligned (264*2 = 33*16)
    __shared__ __align__(16) unsigned short lds_x[32][264];
    // cols 0-255: q (overwritten by attn in P3), 256-511: k. stride 520*2 = 65*16
    __shared__ __align__(16) unsigned short lds_qk[32][520];
    // v transposed [channel][token], stride 40*2 = 5*16; reused as y (32x264) in P4+
    __shared__ __align__(16) unsigned short lds_vt[256][40];
    // P matrices, one slot per wave, pad-free (tiny traffic)
    __shared__ __align__(16) unsigned short lds_p[8][16][16];
    __shared__ float lds_mean[32];
    __shared__ float lds_rstd[32];
    // total: 16896 + 33280 + 20480 + 4096 + 256 = 75008 B -> 2 blocks/CU

    const int tid  = threadIdx.x;
    const int wv   = tid >> 6;        // 0..7
    const int lane = tid & 63;
    const int l15  = lane & 15;
    const int quad = lane >> 4;

    const int w0    = blockIdx.x * 2;
    const int batch = w0 >> 10;
    const int nbase = (w0 & 1023) << 4;
    const long xbase = (long)batch * ((long)C_DIM * NSEQ) + nbase;

    // ---------- Phase 1: x tile (32 tok x 256 ch) -> LDS bf16, vectorized ----------
    {
        const int t4 = (tid & 7) << 2;           // 4 tokens
        const int c4 = (tid >> 3) << 2;          // 4 channels
        float4 r[4];
        #pragma unroll
        for (int j = 0; j < 4; ++j)
            r[j] = *reinterpret_cast<const float4*>(&x[xbase + (long)(c4 + j) * NSEQ + t4]);
        const float* rf = reinterpret_cast<const float*>(r);
        #pragma unroll
        for (int i = 0; i < 4; ++i) {
            uint2 v;
            v.x = pack2(rf[0 * 4 + i], rf[1 * 4 + i]);
            v.y = pack2(rf[2 * 4 + i], rf[3 * 4 + i]);
            *reinterpret_cast<uint2*>(&lds_x[t4 + i][c4]) = v;
        }
    }
    __syncthreads();

    // ---------- Phase 2: QKV = x @ Wqkv^T + b (48 N-tiles / 8 waves) ----------
    for (int i = 0; i < 6; ++i) {
        const int nt = (i << 3) + wv;            // 0..47
        const int d  = nt * 16 + l15;            // 0..767
        const unsigned short* wrow = wq + d * 256 + quad * 8;
        bf16x8 bfr[8];
        #pragma unroll
        for (int k = 0; k < 8; ++k)
            bfr[k] = *reinterpret_cast<const bf16x8*>(wrow + k * 32);
        const float bias = bq[d];
        f32x4 acc0 = {bias, bias, bias, bias};
        f32x4 acc1 = {bias, bias, bias, bias};
        #pragma unroll
        for (int k = 0; k < 8; ++k) {
            bf16x8 a0 = *reinterpret_cast<const bf16x8*>(&lds_x[l15][k * 32 + quad * 8]);
            bf16x8 a1 = *reinterpret_cast<const bf16x8*>(&lds_x[16 + l15][k * 32 + quad * 8]);
            acc0 = __builtin_amdgcn_mfma_f32_16x16x32_bf16(a0, bfr[k], acc0, 0, 0, 0);
            acc1 = __builtin_amdgcn_mfma_f32_16x16x32_bf16(a1, bfr[k], acc1, 0, 0, 0);
        }
        if (d < 512) {                            // q | k (wave-uniform branch)
            #pragma unroll
            for (int r = 0; r < 4; ++r) {
                lds_qk[quad * 4 + r][d]      = f2bf(acc0[r]);
                lds_qk[16 + quad * 4 + r][d] = f2bf(acc1[r]);
            }
        } else {                                  // v transposed
            #pragma unroll
            for (int r = 0; r < 4; ++r) {
                lds_vt[d - 512][quad * 4 + r]      = f2bf(acc0[r]);
                lds_vt[d - 512][16 + quad * 4 + r] = f2bf(acc1[r]);
            }
        }
    }
    __syncthreads();

    // ---------- Phase 3: attention, one (window, head) per wave, no barriers ----------
    {
        const int g = wv >> 2;                   // window in block
        const int h = wv & 3;                    // head
        f32x4 sc = {0.f, 0.f, 0.f, 0.f};
        #pragma unroll
        for (int kk = 0; kk < 2; ++kk) {
            bf16x8 aq = *reinterpret_cast<const bf16x8*>(&lds_qk[g*16 + l15][h*64 + kk*32 + quad*8]);
            bf16x8 bk = *reinterpret_cast<const bf16x8*>(&lds_qk[g*16 + l15][256 + h*64 + kk*32 + quad*8]);
            sc = __builtin_amdgcn_mfma_f32_16x16x32_bf16(aq, bk, sc, 0, 0, 0);
        }
        #pragma unroll
        for (int r = 0; r < 4; ++r) {
            float s = sc[r] * 0.125f;            // 1/sqrt(hd)
            float m = s;
            #pragma unroll
            for (int msk = 1; msk <= 8; msk <<= 1) m = fmaxf(m, __shfl_xor(m, msk, 16));
            float e = __expf(s - m);
            float su = e;
            #pragma unroll
            for (int msk = 1; msk <= 8; msk <<= 1) su += __shfl_xor(su, msk, 16);
            lds_p[wv][quad * 4 + r][l15] = f2bf(e / su);
        }
        // P @ v : K=16 padded to 32 (quads 2,3 zeroed on BOTH operands)
        bf16x8 ap = {0,0,0,0,0,0,0,0};
        if (quad < 2) ap = *reinterpret_cast<const bf16x8*>(&lds_p[wv][l15][quad * 8]);
        #pragma unroll
        for (int dt = 0; dt < 4; ++dt) {
            bf16x8 bv = {0,0,0,0,0,0,0,0};
            if (quad < 2)
                bv = *reinterpret_cast<const bf16x8*>(&lds_vt[h*64 + dt*16 + l15][g*16 + quad*8]);
            f32x4 acc = {0.f, 0.f, 0.f, 0.f};
            acc = __builtin_amdgcn_mfma_f32_16x16x32_bf16(ap, bv, acc, 0, 0, 0);
            #pragma unroll
            for (int r = 0; r < 4; ++r)          // overlay attn onto this wave's own q rect
                lds_qk[g*16 + quad*4 + r][h*64 + dt*16 + l15] = f2bf(acc[r]);
        }
    }
    __syncthreads();

    // ---------- Phase 4: out = attn @ Wo^T + b_o; y = out + x (bf16, overlaid on vt) ----------
    unsigned short* ldy = &lds_vt[0][0];         // 32 x 264 = 8448 <= 10240 shorts
    for (int i = 0; i < 2; ++i) {
        const int nt = (i << 3) + wv;            // 0..15
        const int d  = nt * 16 + l15;            // 0..255
        const unsigned short* wrow = wo + d * 256 + quad * 8;
        bf16x8 bfr[8];
        #pragma unroll
        for (int k = 0; k < 8; ++k)
            bfr[k] = *reinterpret_cast<const bf16x8*>(wrow + k * 32);
        const float bias = bo[d];
        f32x4 acc0 = {bias, bias, bias, bias};
        f32x4 acc1 = {bias, bias, bias, bias};
        #pragma unroll
        for (int k = 0; k < 8; ++k) {
            bf16x8 a0 = *reinterpret_cast<const bf16x8*>(&lds_qk[l15][k * 32 + quad * 8]);
            bf16x8 a1 = *reinterpret_cast<const bf16x8*>(&lds_qk[16 + l15][k * 32 + quad * 8]);
            acc0 = __builtin_amdgcn_mfma_f32_16x16x32_bf16(a0, bfr[k], acc0, 0, 0, 0);
            acc1 = __builtin_amdgcn_mfma_f32_16x16x32_bf16(a1, bfr[k], acc1, 0, 0, 0);
        }
        #pragma unroll
        for (int r = 0; r < 4; ++r) {
            const int r0 = quad * 4 + r;
            ldy[r0 * 264 + d]        = f2bf(acc0[r] + bf2f(lds_x[r0][d]));
            ldy[(16 + r0) * 264 + d] = f2bf(acc1[r] + bf2f(lds_x[16 + r0][d]));
        }
    }
    __syncthreads();

    // ---------- Phase 5a: LN stats (16 threads per token row, b128 reads) ----------
    {
        const int row = tid >> 4, part = tid & 15;
        float s = 0.f, sq = 0.f;
        #pragma unroll
        for (int half = 0; half < 2; ++half) {
            bf16x8 yv = *reinterpret_cast<const bf16x8*>(&ldy[row * 264 + part * 16 + half * 8]);
            #pragma unroll
            for (int ii = 0; ii < 8; ++ii) {
                float v = bf2f((unsigned short)yv[ii]);
                s += v; sq += v * v;
            }
        }
        #pragma unroll
        for (int msk = 1; msk <= 8; msk <<= 1) {
            s  += __shfl_xor(s,  msk, 16);
            sq += __shfl_xor(sq, msk, 16);
        }
        if (part == 0) {
            float mean = s * (1.0f / 256.0f);
            float var  = sq * (1.0f / 256.0f) - mean * mean;
            lds_mean[row] = mean;
            lds_rstd[row] = rsqrtf(var + 1e-5f);
        }
    }
    __syncthreads();

    // ---------- Phase 5b: normalize + vectorized transposed store ----------
    {
        const int t4 = (tid & 7) << 2;
        const int c0 = tid >> 3;                 // 0..63
        float mean[4], rstd[4];
        #pragma unroll
        for (int i = 0; i < 4; ++i) { mean[i] = lds_mean[t4 + i]; rstd[i] = lds_rstd[t4 + i]; }
        #pragma unroll
        for (int it = 0; it < 4; ++it) {
            const int c = c0 + (it << 6);
            const float g = lng[c], b = lnb[c];
            float4 o;
            float* of = reinterpret_cast<float*>(&o);
            #pragma unroll
            for (int i = 0; i < 4; ++i)
                of[i] = (bf2f(ldy[(t4 + i) * 264 + c]) - mean[i]) * rstd[i] * g + b;
            *reinterpret_cast<float4*>(&out[xbase + (long)c * NSEQ + t4]) = o;
        }
    }
}

extern "C" void kernel_launch(void* const* d_in, const int* in_sizes, int n_in,
                              void* d_out, int out_size, void* d_ws, size_t ws_size,
                              hipStream_t stream) {
    const float* x   = (const float*)d_in[0];
    const float* ipw = (const float*)d_in[1];
    const float* ipb = (const float*)d_in[2];
    const float* opw = (const float*)d_in[3];
    const float* opb = (const float*)d_in[4];
    const float* lng = (const float*)d_in[5];
    const float* lnb = (const float*)d_in[6];
    float* out = (float*)d_out;

    unsigned short* wq = (unsigned short*)d_ws;
    unsigned short* wo = wq + 768 * 256;

    prep_weights<<<768, 256, 0, stream>>>(ipw, opw, wq, wo);
    swin_fused<<<4096, 512, 0, stream>>>(x, wq, wo, ipb, opb, lng, lnb, out);
}